// Round 4
// baseline (1406.147 us; speedup 1.0000x reference)
//
#include <hip/hip_runtime.h>
#include <hip/hip_bf16.h>

#define Nn 20000
#define EREL 60000
#define ETOT 180000
#define NG 64
#define FD 384
#define EPS 1e-5f

typedef unsigned short u16;
typedef __attribute__((ext_vector_type(8))) short s8v;     // 8 bf16 (4 VGPR) MFMA A/B frag
typedef __attribute__((ext_vector_type(4))) float f4v;     // MFMA C/D frag

static inline int cdiv(int a, int b) { return (a + b - 1) / b; }

__device__ inline u16 f2b(float f) {
    __hip_bfloat16 h = __float2bfloat16(f);
    union { __hip_bfloat16 b; u16 u; } c; c.b = h; return c.u;
}
__device__ inline float b2f(u16 u) {
    union { __hip_bfloat16 b; u16 u; } c; c.u = u; return __bfloat162float(c.b);
}

// ---------------- split fp32 -> bf16 hi/lo (vectorized by float4) ----------------
__global__ __launch_bounds__(256) void split_k(const float* __restrict__ x,
    u16* __restrict__ hi, u16* __restrict__ lo, int n4)
{
    int i = blockIdx.x * 256 + threadIdx.x;
    if (i >= n4) return;
    float4 v = ((const float4*)x)[i];
    ushort4 h, l;
    h.x = f2b(v.x); l.x = f2b(v.x - b2f(h.x));
    h.y = f2b(v.y); l.y = f2b(v.y - b2f(h.y));
    h.z = f2b(v.z); l.z = f2b(v.z - b2f(h.z));
    h.w = f2b(v.w); l.w = f2b(v.w - b2f(h.w));
    ((ushort4*)hi)[i] = h;
    ((ushort4*)lo)[i] = l;
}

// transpose + split: W[b][K][N] -> T[b][N][K] hi/lo
__global__ void tsplit_k(const float* __restrict__ W, u16* __restrict__ hi,
                         u16* __restrict__ lo, int K, int N, int total)
{
    int idx = blockIdx.x * 256 + threadIdx.x;
    if (idx >= total) return;
    int kn = K * N;
    int b = idx / kn, rem = idx - b * kn;
    int k = rem / N, n = rem - k * N;
    float v = W[idx];
    u16 h = f2b(v), l = f2b(v - b2f(h));
    int o = b * kn + n * K + k;
    hi[o] = h; lo[o] = l;
}

// ---------------- split-bf16 MFMA GEMM ----------------
// C[M,N] = A[M,K] @ B[N,K]^T, A,B bf16 (hi,lo) pairs row-major ld=K. 128x128 tile,
// 4 waves of 64x64, 16x16x32 MFMA, 3-term split.
// GRID: x = column block, y = relation (batches B/C), z = ROW block (slowest) so all
// blocks sharing an A row-strip are dispatch-adjacent -> A fetched from HBM once.
template<bool BIAS, bool RELU, bool STATS>
__global__ __launch_bounds__(256) void mgemm_k(
    const u16* __restrict__ Ahi, const u16* __restrict__ Alo,
    const u16* __restrict__ Bhi, const u16* __restrict__ Blo,
    const float* __restrict__ bias, float* __restrict__ C,
    int M, int K, int ldc, int bstride, float* __restrict__ stats)
{
    __shared__ u16 lds[4 * 128 * 32];   // Ahi | Alo | Bhi | Blo tiles, [128][32] each
    __shared__ float red[256];
    const int t = threadIdx.x;
    const int brow = blockIdx.z * 128, bcol = blockIdx.x * 128;
    const int z = blockIdx.y;
    Bhi += (size_t)z * bstride;
    Blo += (size_t)z * bstride;
    C   += (size_t)z * M * ldc;

    const int r0 = t >> 2, sl = t & 3;
    const int rA0 = min(brow + r0, M - 1);
    const int rA1 = min(brow + r0 + 64, M - 1);
    const u16* gsrc[8];
    gsrc[0] = Ahi + (size_t)rA0 * K + sl * 8;
    gsrc[1] = Ahi + (size_t)rA1 * K + sl * 8;
    gsrc[2] = Alo + (size_t)rA0 * K + sl * 8;
    gsrc[3] = Alo + (size_t)rA1 * K + sl * 8;
    gsrc[4] = Bhi + (size_t)(bcol + r0) * K + sl * 8;
    gsrc[5] = Bhi + (size_t)(bcol + r0 + 64) * K + sl * 8;
    gsrc[6] = Blo + (size_t)(bcol + r0) * K + sl * 8;
    gsrc[7] = Blo + (size_t)(bcol + r0 + 64) * K + sl * 8;
    const int swz = (sl ^ (r0 & 3)) << 3;
    int ldst[8];
    #pragma unroll
    for (int i = 0; i < 8; i++) {
        int tile = i >> 1, row = r0 + 64 * (i & 1);
        ldst[i] = tile * 4096 + row * 32 + swz;
    }

    const int l = t & 63, w = t >> 6;
    const int wr = (w >> 1) * 64, wc = (w & 1) * 64;
    const int lr = l & 15, kq = l >> 4;

    f4v acc[4][4] = {};
    const int NK = K >> 5;

    s8v stg[8];
    #pragma unroll
    for (int i = 0; i < 8; i++) stg[i] = *(const s8v*)gsrc[i];

    for (int kc = 0; kc < NK; kc++) {
        if (kc) __syncthreads();
        #pragma unroll
        for (int i = 0; i < 8; i++) *(s8v*)(lds + ldst[i]) = stg[i];
        __syncthreads();
        if (kc + 1 < NK) {
            const int ko = (kc + 1) * 32;
            #pragma unroll
            for (int i = 0; i < 8; i++) stg[i] = *(const s8v*)(gsrc[i] + ko);
        }
        #define LDR(T, row) (*(const s8v*)(lds + (T) * 4096 + (row) * 32 + ((kq ^ ((row) & 3)) << 3)))
        s8v bh[4], bl[4];
        #pragma unroll
        for (int tn = 0; tn < 4; tn++) {
            int rb = wc + tn * 16 + lr;
            bh[tn] = LDR(2, rb);
            bl[tn] = LDR(3, rb);
        }
        #pragma unroll
        for (int tm = 0; tm < 4; tm++) {
            int ra = wr + tm * 16 + lr;
            s8v ah = LDR(0, ra);
            s8v al = LDR(1, ra);
            #pragma unroll
            for (int tn = 0; tn < 4; tn++) {
                acc[tm][tn] = __builtin_amdgcn_mfma_f32_16x16x32_bf16(ah, bh[tn], acc[tm][tn], 0, 0, 0);
                acc[tm][tn] = __builtin_amdgcn_mfma_f32_16x16x32_bf16(al, bh[tn], acc[tm][tn], 0, 0, 0);
                acc[tm][tn] = __builtin_amdgcn_mfma_f32_16x16x32_bf16(ah, bl[tn], acc[tm][tn], 0, 0, 0);
            }
        }
        #undef LDR
    }

    float s1 = 0.f, s2 = 0.f;
    #pragma unroll
    for (int tm = 0; tm < 4; tm++) {
        #pragma unroll
        for (int rg = 0; rg < 4; rg++) {
            int row = brow + wr + tm * 16 + kq * 4 + rg;
            if (row < M) {
                #pragma unroll
                for (int tn = 0; tn < 4; tn++) {
                    int col = bcol + wc + tn * 16 + lr;
                    float v = acc[tm][tn][rg];
                    if (BIAS) v += bias[col];
                    if (RELU) v = fmaxf(v, 0.f);
                    C[(size_t)row * ldc + col] = v;
                    if (STATS) { s1 += v; s2 += v * v; }
                }
            }
        }
    }
    if (STATS) {
        __syncthreads();
        red[t] = s1; __syncthreads();
        for (int o = 128; o; o >>= 1) { if (t < o) red[t] += red[t + o]; __syncthreads(); }
        if (t == 0) atomicAdd(&stats[0], red[0]);
        __syncthreads();
        red[t] = s2; __syncthreads();
        for (int o = 128; o; o >>= 1) { if (t < o) red[t] += red[t + o]; __syncthreads(); }
        if (t == 0) atomicAdd(&stats[1], red[0]);
    }
}

// ---------------- fp32 tiled GEMM (tiny-K shapes: geo K=6, pri K=33, cls2) ----------------
template<bool BIAS, bool RELU, bool STATS>
__global__ __launch_bounds__(256) void sgemm_k(
    const float* __restrict__ A, const float* __restrict__ B,
    const float* __restrict__ bias, float* __restrict__ C,
    int M, int K, int N, int ldc, float* __restrict__ stats)
{
    const int BK = 16;
    const int r = blockIdx.z;
    B += (size_t)r * K * N;
    C += (size_t)r * M * ldc;
    __shared__ float As[16][65];
    __shared__ float Bs[16][64];
    int tid = threadIdx.x;
    int tx = tid & 15, ty = tid >> 4;
    int brow = blockIdx.x * 64, bcol = blockIdx.y * 64;
    float acc[4][4] = {};
    for (int k0 = 0; k0 < K; k0 += BK) {
        #pragma unroll
        for (int i = 0; i < 4; i++) {
            int e = tid + 256 * i;
            int ar = e >> 4, ak = e & 15;
            int gr = brow + ar, gk = k0 + ak;
            As[ak][ar] = (gr < M && gk < K) ? A[(size_t)gr * K + gk] : 0.f;
            int bk = e >> 6, bn = e & 63;
            int gbk = k0 + bk, gbn = bcol + bn;
            Bs[bk][bn] = (gbk < K && gbn < N) ? B[(size_t)gbk * N + gbn] : 0.f;
        }
        __syncthreads();
        #pragma unroll
        for (int k = 0; k < BK; k++) {
            float ra[4], rb[4];
            #pragma unroll
            for (int i = 0; i < 4; i++) ra[i] = As[k][ty * 4 + i];
            #pragma unroll
            for (int j = 0; j < 4; j++) rb[j] = Bs[k][tx * 4 + j];
            #pragma unroll
            for (int i = 0; i < 4; i++)
                #pragma unroll
                for (int j = 0; j < 4; j++)
                    acc[i][j] = fmaf(ra[i], rb[j], acc[i][j]);
        }
        __syncthreads();
    }
    float s1 = 0.f, s2 = 0.f;
    #pragma unroll
    for (int i = 0; i < 4; i++) {
        int row = brow + ty * 4 + i;
        #pragma unroll
        for (int j = 0; j < 4; j++) {
            int col = bcol + tx * 4 + j;
            if (row < M && col < N) {
                float v = acc[i][j];
                if (BIAS) v += bias[col];
                if (RELU) v = v > 0.f ? v : 0.f;
                C[(size_t)row * ldc + col] = v;
                if (STATS) { s1 += v; s2 += v * v; }
            }
        }
    }
    if (STATS) {
        __shared__ float red[256];
        __syncthreads();
        red[tid] = s1; __syncthreads();
        for (int o = 128; o; o >>= 1) { if (tid < o) red[tid] += red[tid + o]; __syncthreads(); }
        if (tid == 0) atomicAdd(&stats[0], red[0]);
        __syncthreads();
        red[tid] = s2; __syncthreads();
        for (int o = 128; o; o >>= 1) { if (tid < o) red[tid] += red[tid + o]; __syncthreads(); }
        if (tid == 0) atomicAdd(&stats[1], red[0]);
    }
}

// scalar-LN of a 128-col block of H (pre-offset) from RAW sums (finalized inline),
// fused bf16 hi/lo split into hi/lo (pre-offset).
__global__ __launch_bounds__(256) void enc_norm_k(float* __restrict__ H, const float* __restrict__ w,
                           const float* __restrict__ b, const float* __restrict__ stats,
                           float cntinv, u16* __restrict__ hi, u16* __restrict__ lo)
{
    int i = blockIdx.x * 256 + threadIdx.x;   // float4 index within the 128-col block
    if (i >= Nn * 32) return;
    int n = i >> 5, c4 = i & 31;
    float m = stats[0] * cntinv;
    float var = stats[1] * cntinv - m * m;
    float s = 1.f / (sqrtf(fmaxf(var, 0.f)) + EPS);
    float4 wv = ((const float4*)w)[c4];
    float4 bv = ((const float4*)b)[c4];
    float4* p = (float4*)(H + (size_t)n * FD) + c4;
    float4 v = *p;
    v.x = (v.x - m) * s * wv.x + bv.x;
    v.y = (v.y - m) * s * wv.y + bv.y;
    v.z = (v.z - m) * s * wv.z + bv.z;
    v.w = (v.w - m) * s * wv.w + bv.w;
    *p = v;
    ushort4 hh, ll;
    hh.x = f2b(v.x); ll.x = f2b(v.x - b2f(hh.x));
    hh.y = f2b(v.y); ll.y = f2b(v.y - b2f(hh.y));
    hh.z = f2b(v.z); ll.z = f2b(v.z - b2f(hh.z));
    hh.w = f2b(v.w); ll.w = f2b(v.w - b2f(hh.w));
    ((ushort4*)(hi + (size_t)n * FD))[c4] = hh;
    ((ushort4*)(lo + (size_t)n * FD))[c4] = ll;
}

// qi[r,n,h] = xr[r,n,:] . q[:,h] ; kj likewise. One wave per (r,n) row.
__global__ __launch_bounds__(256) void proj_qk_k(const float* __restrict__ xr,
    const float* __restrict__ q, const float* __restrict__ kk,
    float* __restrict__ qi, float* __restrict__ kj)
{
    int row = blockIdx.x * 4 + (threadIdx.x >> 6);
    int lane = threadIdx.x & 63;
    if (row >= 3 * Nn) return;
    const float* xrow = xr + (size_t)row * FD;
    float pq[8] = {}, pk[8] = {};
    #pragma unroll
    for (int j = 0; j < 6; j++) {
        int c = lane + 64 * j;
        float x = xrow[c];
        #pragma unroll
        for (int h = 0; h < 8; h++) {
            pq[h] = fmaf(x, q[c * 8 + h], pq[h]);
            pk[h] = fmaf(x, kk[c * 8 + h], pk[h]);
        }
    }
    #pragma unroll
    for (int o = 32; o; o >>= 1) {
        #pragma unroll
        for (int h = 0; h < 8; h++) {
            pq[h] += __shfl_down(pq[h], o);
            pk[h] += __shfl_down(pk[h], o);
        }
    }
    if (lane == 0) {
        #pragma unroll
        for (int h = 0; h < 8; h++) {
            qi[(size_t)row * 8 + h] = pq[h];
            kj[(size_t)row * 8 + h] = pk[h];
        }
    }
}

__global__ void edge_count_k(const int* __restrict__ e0, const int* __restrict__ e1,
                             const int* __restrict__ e2, int* __restrict__ cnt)
{
    int e = blockIdx.x * 256 + threadIdx.x;
    if (e >= ETOT) return;
    int r = e / EREL, i = e - r * EREL;
    const int* ei = (r == 0) ? e0 : (r == 1) ? e1 : e2;
    atomicAdd(&cnt[ei[EREL + i]], 1);
}

__global__ void edge_fill_k(const int* __restrict__ e0, const int* __restrict__ e1,
                            const int* __restrict__ e2, int* __restrict__ cursor,
                            int* __restrict__ eidx)
{
    int e = blockIdx.x * 256 + threadIdx.x;
    if (e >= ETOT) return;
    int r = e / EREL, i = e - r * EREL;
    const int* ei = (r == 0) ? e0 : (r == 1) ? e1 : e2;
    int src = ei[i], dst = ei[EREL + i];
    int pos = atomicAdd(&cursor[dst], 1);
    eidx[pos] = src | (r << 24);
}

__global__ __launch_bounds__(1024) void scan_k(const int* __restrict__ cnt,
                                               int* __restrict__ rowptr, int* __restrict__ cursor)
{
    __shared__ int lds[1024];
    __shared__ int carry;
    int t = threadIdx.x;
    if (t == 0) carry = 0;
    __syncthreads();
    for (int base = 0; base < Nn; base += 1024) {
        int i = base + t;
        int v = (i < Nn) ? cnt[i] : 0;
        lds[t] = v; __syncthreads();
        for (int o = 1; o < 1024; o <<= 1) {
            int x = (t >= o) ? lds[t - o] : 0;
            __syncthreads();
            lds[t] += x;
            __syncthreads();
        }
        int c = carry;
        if (i < Nn) { int ex = c + lds[t] - v; rowptr[i] = ex; cursor[i] = ex; }
        __syncthreads();
        if (t == 1023) carry = c + lds[1023];
        __syncthreads();
    }
    if (t == 0) rowptr[Nn] = carry;
}

__global__ void gcount_k(const int* __restrict__ batch, int* __restrict__ gcnt)
{
    int n = blockIdx.x * 256 + threadIdx.x;
    if (n >= Nn) return;
    atomicAdd(&gcnt[batch[n]], 1);
}

// RGAT aggregation: one wave per dst node (CSR). Softmax node-local.
__global__ __launch_bounds__(256) void aggr_k(const float* __restrict__ xr,
    const float* __restrict__ qi, const float* __restrict__ kj,
    const int* __restrict__ rowptr, const int* __restrict__ eidx,
    const float* __restrict__ bias, float* __restrict__ out)
{
    int node = blockIdx.x * 4 + (threadIdx.x >> 6);
    int lane = threadIdx.x & 63;
    if (node >= Nn) return;
    int e0 = rowptr[node], e1 = rowptr[node + 1];
    float qv = (lane < 24) ? qi[(size_t)(lane >> 3) * Nn * 8 + (size_t)node * 8 + (lane & 7)] : 0.f;
    float den = 0.f;
    for (int e = e0; e < e1; e++) {
        int p = eidx[e];
        int srcn = p & 0xFFFFFF, et = p >> 24;
        float kv = (lane < 8) ? kj[((size_t)et * Nn + srcn) * 8 + lane] : 0.f;
        float qq = __shfl(qv, et * 8 + (lane & 7));
        float al = qq + kv;
        al = (al > 0.f) ? al : 0.2f * al;
        den += __expf(al);
    }
    int hd[6]; float rcp[6];
    #pragma unroll
    for (int j = 0; j < 6; j++) {
        hd[j] = (lane + 64 * j) / 48;
        float dh = __shfl(den, hd[j]);
        rcp[j] = 1.f / (dh + 1e-16f);
    }
    float acc[6] = {};
    for (int e = e0; e < e1; e++) {
        int p = eidx[e];
        int srcn = p & 0xFFFFFF, et = p >> 24;
        float kv = (lane < 8) ? kj[((size_t)et * Nn + srcn) * 8 + lane] : 0.f;
        float qq = __shfl(qv, et * 8 + (lane & 7));
        float al = qq + kv;
        al = (al > 0.f) ? al : 0.2f * al;
        float ex = __expf(al);
        const float* row = xr + ((size_t)et * Nn + srcn) * FD;
        #pragma unroll
        for (int j = 0; j < 6; j++) {
            float a = __shfl(ex, hd[j]) * rcp[j];
            acc[j] = fmaf(a, row[lane + 64 * j], acc[j]);
        }
    }
    #pragma unroll
    for (int j = 0; j < 6; j++)
        out[(size_t)node * FD + lane + 64 * j] = acc[j] + bias[lane + 64 * j];
}

// elu + residual (in place) + per-graph sum/sumsq. One wave per 4 nodes, coalesced float2.
// LDS bins -> 1 global atomic per (block, graph).
__global__ __launch_bounds__(256) void post_k(float* __restrict__ y, const float* __restrict__ prev,
    const int* __restrict__ batch, float* __restrict__ gsum, float* __restrict__ gsq)
{
    __shared__ float ls[NG], lq[NG];
    int t = threadIdx.x;
    if (t < NG) { ls[t] = 0.f; lq[t] = 0.f; }
    __syncthreads();
    int wave = (blockIdx.x * 256 + t) >> 6;
    int lane = t & 63;
    int n0 = wave * 4;
    float s1 = 0.f, s2 = 0.f; int curg = -1;
    for (int k = 0; k < 4; k++) {
        int n = n0 + k;
        if (n >= Nn) break;
        int g = batch[n];                      // wave-uniform
        if (g != curg && curg >= 0) {
            float a = s1, bq = s2;
            #pragma unroll
            for (int o = 32; o; o >>= 1) { a += __shfl_down(a, o); bq += __shfl_down(bq, o); }
            if (lane == 0) { atomicAdd(&ls[curg], a); atomicAdd(&lq[curg], bq); }
            s1 = 0.f; s2 = 0.f;
        }
        curg = g;
        float2* yp = (float2*)(y + (size_t)n * FD);
        const float2* pp = (const float2*)(prev + (size_t)n * FD);
        #pragma unroll
        for (int j = 0; j < 3; j++) {
            float2 v = yp[lane + 64 * j];
            float2 p = pp[lane + 64 * j];
            v.x = ((v.x > 0.f) ? v.x : expm1f(v.x)) + p.x;
            v.y = ((v.y > 0.f) ? v.y : expm1f(v.y)) + p.y;
            yp[lane + 64 * j] = v;
            s1 += v.x + v.y; s2 += v.x * v.x + v.y * v.y;
        }
    }
    if (curg >= 0) {
        float a = s1, bq = s2;
        #pragma unroll
        for (int o = 32; o; o >>= 1) { a += __shfl_down(a, o); bq += __shfl_down(bq, o); }
        if (lane == 0) { atomicAdd(&ls[curg], a); atomicAdd(&lq[curg], bq); }
    }
    __syncthreads();
    if (t < NG && (ls[t] != 0.f || lq[t] != 0.f)) {
        atomicAdd(&gsum[t], ls[t]);
        atomicAdd(&gsq[t], lq[t]);
    }
}

// graph-LN (stats finalized inline from raw sums) + fused bf16 hi/lo split
__global__ __launch_bounds__(256) void gnorm_split_k(float* __restrict__ y,
    const int* __restrict__ batch, const float* __restrict__ gsum, const float* __restrict__ gsq,
    const int* __restrict__ gcnt, const float* __restrict__ w, const float* __restrict__ b,
    u16* __restrict__ hi, u16* __restrict__ lo)
{
    int i = blockIdx.x * 256 + threadIdx.x;   // float4 index
    if (i >= Nn * (FD / 4)) return;
    int n = i / 96, c4 = i - n * 96;
    int g = batch[n];
    float norm = fmaxf((float)gcnt[g], 1.f) * (float)FD;
    float m = gsum[g] / norm;
    float var = gsq[g] / norm - m * m;
    float rstd = rsqrtf(var + EPS);
    float4 wv = ((const float4*)w)[c4];
    float4 bv = ((const float4*)b)[c4];
    float4 v = ((const float4*)y)[i];
    v.x = (v.x - m) * rstd * wv.x + bv.x;
    v.y = (v.y - m) * rstd * wv.y + bv.y;
    v.z = (v.z - m) * rstd * wv.z + bv.z;
    v.w = (v.w - m) * rstd * wv.w + bv.w;
    ((float4*)y)[i] = v;
    ushort4 hh, ll;
    hh.x = f2b(v.x); ll.x = f2b(v.x - b2f(hh.x));
    hh.y = f2b(v.y); ll.y = f2b(v.y - b2f(hh.y));
    hh.z = f2b(v.z); ll.z = f2b(v.z - b2f(hh.z));
    hh.w = f2b(v.w); ll.w = f2b(v.w - b2f(hh.w));
    ((ushort4*)hi)[i] = hh;
    ((ushort4*)lo)[i] = ll;
}

__global__ void softmax_prior_k(const float* __restrict__ logits, float* __restrict__ prior)
{
    int n = blockIdx.x * 8 + (threadIdx.x >> 5);
    int l = threadIdx.x & 31;
    if (n >= Nn) return;
    float v = logits[n * 32 + l];
    float m = v;
    #pragma unroll
    for (int o = 16; o; o >>= 1) m = fmaxf(m, __shfl_xor(m, o, 32));
    float e = __expf(v - m);
    float s = e;
    #pragma unroll
    for (int o = 16; o; o >>= 1) s += __shfl_xor(s, o, 32);
    prior[(size_t)n * 33 + l] = e / s;
    if (l == 0) prior[(size_t)n * 33 + 32] = 1.f / s;
}

extern "C" void kernel_launch(void* const* d_in, const int* in_sizes, int n_in,
                              void* d_out, int out_size, void* d_ws, size_t ws_size,
                              hipStream_t stream)
{
    const float* x_visual = (const float*)d_in[0];
    const float* x_geom   = (const float*)d_in[1];
    const float* x_prior  = (const float*)d_in[2];
    const int* ei0   = (const int*)d_in[3];
    const int* ei1   = (const int*)d_in[4];
    const int* ei2   = (const int*)d_in[5];
    const int* batch = (const int*)d_in[6];
    const float* vis_W = (const float*)d_in[7];  const float* vis_b = (const float*)d_in[8];
    const float* vis_lnw = (const float*)d_in[9]; const float* vis_lnb = (const float*)d_in[10];
    const float* geo_W = (const float*)d_in[11]; const float* geo_b = (const float*)d_in[12];
    const float* geo_lnw = (const float*)d_in[13]; const float* geo_lnb = (const float*)d_in[14];
    const float* pri_W = (const float*)d_in[15]; const float* pri_b = (const float*)d_in[16];
    const float* pri_lnw = (const float*)d_in[17]; const float* pri_lnb = (const float*)d_in[18];
    const float* rgat_W[2]    = { (const float*)d_in[19], (const float*)d_in[25] };
    const float* rgat_q[2]    = { (const float*)d_in[20], (const float*)d_in[26] };
    const float* rgat_kk[2]   = { (const float*)d_in[21], (const float*)d_in[27] };
    const float* rgat_bias[2] = { (const float*)d_in[22], (const float*)d_in[28] };
    const float* ln_w[2]      = { (const float*)d_in[23], (const float*)d_in[29] };
    const float* ln_b[2]      = { (const float*)d_in[24], (const float*)d_in[30] };
    const float* cls_W1 = (const float*)d_in[31]; const float* cls_b1 = (const float*)d_in[32];
    const float* cls_W2 = (const float*)d_in[33]; const float* cls_b2 = (const float*)d_in[34];
    float* OUT = (float*)d_out;

    // ---------------- workspace layout ----------------
    float* ws = (float*)d_ws;
    float* XR    = ws;                         // 23.04M floats (92.2 MB)
    float* HCAT  = XR + (size_t)3 * Nn * FD;
    float* HA    = HCAT + (size_t)Nn * FD;
    float* HB    = HA + (size_t)Nn * FD;
    float* PRIOR = HB + (size_t)Nn * FD;       // Nn*33
    float* QI    = PRIOR + (size_t)Nn * 33;
    float* KJ    = QI + (size_t)3 * Nn * 8;
    u16* HS0_HI  = (u16*)(KJ + (size_t)3 * Nn * 8);   // HCAT split
    u16* HS0_LO  = HS0_HI + (size_t)Nn * FD;
    u16* HS1_HI  = HS0_LO + (size_t)Nn * FD;          // HA split
    u16* HS1_LO  = HS1_HI + (size_t)Nn * FD;
    u16* RW_HI   = HS1_LO + (size_t)Nn * FD;   // 2*3*384*384
    u16* RW_LO   = RW_HI + (size_t)2 * 3 * 384 * 384;
    u16* VW_HI   = RW_LO + (size_t)2 * 3 * 384 * 384; // 128*1024
    u16* VW_LO   = VW_HI + (size_t)128 * 1024;
    u16* CW_HI   = VW_LO + (size_t)128 * 1024;        // 128*384
    u16* CW_LO   = CW_HI + (size_t)128 * 384;
    float* STATS = (float*)(CW_LO + (size_t)128 * 384); // 2
    float* GSUM  = STATS + 2;                  // 64
    float* GSQ   = GSUM + 64;
    int* CNT    = (int*)(GSQ + 64);
    int* ROWPTR = CNT + Nn;
    int* CURSOR = ROWPTR + Nn + 1;
    int* EIDX   = CURSOR + Nn;
    int* GCNT   = EIDX + ETOT;
    // aliases into XR (temporally dead regions):
    u16* VA_HI = (u16*)XR;                     // x_visual split: [0, 82MB), dead after vis gemm
    u16* VA_LO = VA_HI + (size_t)Nn * 1024;
    float* CLSH = XR;                          // classifier hidden: [0, 10.3MB), after last aggr
    u16* HS2_HI = (u16*)(XR + (size_t)12 * 1000 * 1000); // HB split: [48MB, 78.7MB), after last aggr
    u16* HS2_LO = HS2_HI + (size_t)Nn * FD;

    // ---------------- CSR build (reused by all 4 RGAT calls) ----------------
    hipMemsetAsync(CNT, 0, Nn * sizeof(int), stream);
    edge_count_k<<<cdiv(ETOT, 256), 256, 0, stream>>>(ei0, ei1, ei2, CNT);
    scan_k<<<1, 1024, 0, stream>>>(CNT, ROWPTR, CURSOR);
    edge_fill_k<<<cdiv(ETOT, 256), 256, 0, stream>>>(ei0, ei1, ei2, CURSOR, EIDX);
    hipMemsetAsync(GCNT, 0, 64 * sizeof(int), stream);
    gcount_k<<<cdiv(Nn, 256), 256, 0, stream>>>(batch, GCNT);

    // ---------------- weight + x_visual conversions ----------------
    tsplit_k<<<cdiv(3 * 384 * 384, 256), 256, 0, stream>>>(rgat_W[0], RW_HI, RW_LO, 384, 384, 3 * 384 * 384);
    tsplit_k<<<cdiv(3 * 384 * 384, 256), 256, 0, stream>>>(rgat_W[1], RW_HI + 3 * 384 * 384, RW_LO + 3 * 384 * 384, 384, 384, 3 * 384 * 384);
    tsplit_k<<<cdiv(1024 * 128, 256), 256, 0, stream>>>(vis_W, VW_HI, VW_LO, 1024, 128, 1024 * 128);
    tsplit_k<<<cdiv(384 * 128, 256), 256, 0, stream>>>(cls_W1, CW_HI, CW_LO, 384, 128, 384 * 128);
    split_k<<<cdiv(Nn * 1024 / 4, 256), 256, 0, stream>>>(x_visual, VA_HI, VA_LO, Nn * 1024 / 4);

    const int MB = cdiv(Nn, 128);   // 157
    const int POSTB = cdiv(cdiv(Nn, 4) * 64, 256);  // 1250

    // ---------------- vis encoder (MFMA) -> HCAT[:,0:128) ----------------
    hipMemsetAsync(STATS, 0, 2 * sizeof(float), stream);
    mgemm_k<true, true, true><<<dim3(1, 1, MB), 256, 0, stream>>>(
        VA_HI, VA_LO, VW_HI, VW_LO, vis_b, HCAT, Nn, 1024, FD, 0, STATS);
    enc_norm_k<<<cdiv(Nn * 32, 256), 256, 0, stream>>>(HCAT, vis_lnw, vis_lnb, STATS, 1.f / ((float)Nn * 128.f), HS0_HI, HS0_LO);

    // ---------------- geo encoder (fp32, K=6) -> HCAT[:,128:256) ----------------
    dim3 genc(cdiv(Nn, 64), 2, 1);
    hipMemsetAsync(STATS, 0, 2 * sizeof(float), stream);
    sgemm_k<true, true, true><<<genc, 256, 0, stream>>>(x_geom, geo_W, geo_b, HCAT + 128, Nn, 6, 128, FD, STATS);
    enc_norm_k<<<cdiv(Nn * 32, 256), 256, 0, stream>>>(HCAT + 128, geo_lnw, geo_lnb, STATS, 1.f / ((float)Nn * 128.f), HS0_HI + 128, HS0_LO + 128);

    for (int t = 0; t < 2; t++) {
        // prior encoder (fp32, K=33) -> HCAT[:,256:384)
        const float* pin = t ? PRIOR : x_prior;
        hipMemsetAsync(STATS, 0, 2 * sizeof(float), stream);
        sgemm_k<true, true, true><<<genc, 256, 0, stream>>>(pin, pri_W, pri_b, HCAT + 256, Nn, 33, 128, FD, STATS);
        enc_norm_k<<<cdiv(Nn * 32, 256), 256, 0, stream>>>(HCAT + 256, pri_lnw, pri_lnb, STATS, 1.f / ((float)Nn * 128.f), HS0_HI + 256, HS0_LO + 256);

        float* hin = HCAT;
        for (int L = 0; L < 2; L++) {
            float* hout = L ? HB : HA;
            const u16* ahi = L ? HS1_HI : HS0_HI;
            const u16* alo = L ? HS1_LO : HS0_LO;
            u16* shi = L ? HS2_HI : HS1_HI;
            u16* slo = L ? HS2_LO : HS1_LO;
            mgemm_k<false, false, false><<<dim3(3, 3, MB), 256, 0, stream>>>(
                ahi, alo, RW_HI + (size_t)L * 3 * 384 * 384, RW_LO + (size_t)L * 3 * 384 * 384,
                nullptr, XR, Nn, 384, FD, 384 * 384, nullptr);
            proj_qk_k<<<cdiv(3 * Nn, 4), 256, 0, stream>>>(XR, rgat_q[L], rgat_kk[L], QI, KJ);
            aggr_k<<<cdiv(Nn, 4), 256, 0, stream>>>(XR, QI, KJ, ROWPTR, EIDX, rgat_bias[L], hout);
            hipMemsetAsync(GSUM, 0, 128 * sizeof(float), stream);  // GSUM+GSQ contiguous
            post_k<<<POSTB, 256, 0, stream>>>(hout, hin, batch, GSUM, GSQ);
            gnorm_split_k<<<cdiv(Nn * 96, 256), 256, 0, stream>>>(hout, batch, GSUM, GSQ, GCNT, ln_w[L], ln_b[L], shi, slo);
            hin = hout;
        }

        // classifier: cls1 (MFMA, reads HS2 split) -> CLSH, cls2 (fp32) -> OUT
        mgemm_k<true, true, false><<<dim3(1, 1, MB), 256, 0, stream>>>(
            HS2_HI, HS2_LO, CW_HI, CW_LO, cls_b1, CLSH, Nn, 384, 128, 0, nullptr);
        sgemm_k<true, false, false><<<dim3(cdiv(Nn, 64), 1, 1), 256, 0, stream>>>(
            CLSH, cls_W2, cls_b2, OUT, Nn, 128, 32, 32, nullptr);

        if (t == 0)
            softmax_prior_k<<<cdiv(Nn, 8), 256, 0, stream>>>(OUT, PRIOR);
    }
}

// Round 5
// 1339.127 us; speedup vs baseline: 1.0500x; 1.0500x over previous
//
#include <hip/hip_runtime.h>
#include <hip/hip_bf16.h>

#define Nn 20000
#define EREL 60000
#define ETOT 180000
#define NG 64
#define FD 384
#define EPS 1e-5f

typedef unsigned short u16;
typedef __attribute__((ext_vector_type(8))) short s8v;     // 8 bf16 (4 VGPR) MFMA A/B frag
typedef __attribute__((ext_vector_type(4))) float f4v;     // MFMA C/D frag

static inline int cdiv(int a, int b) { return (a + b - 1) / b; }

__device__ inline u16 f2b(float f) {
    __hip_bfloat16 h = __float2bfloat16(f);
    union { __hip_bfloat16 b; u16 u; } c; c.b = h; return c.u;
}
__device__ inline float b2f(u16 u) {
    union { __hip_bfloat16 b; u16 u; } c; c.u = u; return __bfloat162float(c.b);
}

// ---------------- split fp32 -> bf16 hi/lo (vectorized by float4) ----------------
__global__ __launch_bounds__(256) void split_k(const float* __restrict__ x,
    u16* __restrict__ hi, u16* __restrict__ lo, int n4)
{
    int i = blockIdx.x * 256 + threadIdx.x;
    if (i >= n4) return;
    float4 v = ((const float4*)x)[i];
    ushort4 h, l;
    h.x = f2b(v.x); l.x = f2b(v.x - b2f(h.x));
    h.y = f2b(v.y); l.y = f2b(v.y - b2f(h.y));
    h.z = f2b(v.z); l.z = f2b(v.z - b2f(h.z));
    h.w = f2b(v.w); l.w = f2b(v.w - b2f(h.w));
    ((ushort4*)hi)[i] = h;
    ((ushort4*)lo)[i] = l;
}

// transpose + split: W[b][K][N] -> T[b][N][K] hi/lo
__global__ void tsplit_k(const float* __restrict__ W, u16* __restrict__ hi,
                         u16* __restrict__ lo, int K, int N, int total)
{
    int idx = blockIdx.x * 256 + threadIdx.x;
    if (idx >= total) return;
    int kn = K * N;
    int b = idx / kn, rem = idx - b * kn;
    int k = rem / N, n = rem - k * N;
    float v = W[idx];
    u16 h = f2b(v), l = f2b(v - b2f(h));
    int o = b * kn + n * K + k;
    hi[o] = h; lo[o] = l;
}

// ---------------- split-bf16 MFMA GEMM ----------------
// C[M,N] = A[M,K] @ B[N,K]^T, A,B bf16 (hi,lo) pairs row-major ld=K. 128x128 tile,
// 4 waves of 64x64, 16x16x32 MFMA, 3-term split. blockIdx.z batches B/C.
// OB16: round result to bf16 at store (fp32 accumulate throughout).
template<bool BIAS, bool RELU, bool STATS, bool OB16>
__global__ __launch_bounds__(256) void mgemm_k(
    const u16* __restrict__ Ahi, const u16* __restrict__ Alo,
    const u16* __restrict__ Bhi, const u16* __restrict__ Blo,
    const float* __restrict__ bias, void* __restrict__ Cv,
    int M, int K, int ldc, int bstride, float* __restrict__ stats)
{
    __shared__ u16 lds[4 * 128 * 32];   // Ahi | Alo | Bhi | Blo tiles, [128][32] each
    __shared__ float red[256];
    const int t = threadIdx.x;
    const int brow = blockIdx.x * 128, bcol = blockIdx.y * 128;
    const int z = blockIdx.z;
    Bhi += (size_t)z * bstride;
    Blo += (size_t)z * bstride;
    float* Cf = OB16 ? nullptr : (float*)Cv + (size_t)z * M * ldc;
    u16*   Ch = OB16 ? (u16*)Cv + (size_t)z * M * ldc : nullptr;

    const int r0 = t >> 2, sl = t & 3;
    const int rA0 = min(brow + r0, M - 1);
    const int rA1 = min(brow + r0 + 64, M - 1);
    const u16* gsrc[8];
    gsrc[0] = Ahi + (size_t)rA0 * K + sl * 8;
    gsrc[1] = Ahi + (size_t)rA1 * K + sl * 8;
    gsrc[2] = Alo + (size_t)rA0 * K + sl * 8;
    gsrc[3] = Alo + (size_t)rA1 * K + sl * 8;
    gsrc[4] = Bhi + (size_t)(bcol + r0) * K + sl * 8;
    gsrc[5] = Bhi + (size_t)(bcol + r0 + 64) * K + sl * 8;
    gsrc[6] = Blo + (size_t)(bcol + r0) * K + sl * 8;
    gsrc[7] = Blo + (size_t)(bcol + r0 + 64) * K + sl * 8;
    const int swz = (sl ^ (r0 & 3)) << 3;
    int ldst[8];
    #pragma unroll
    for (int i = 0; i < 8; i++) {
        int tile = i >> 1, row = r0 + 64 * (i & 1);
        ldst[i] = tile * 4096 + row * 32 + swz;
    }

    const int l = t & 63, w = t >> 6;
    const int wr = (w >> 1) * 64, wc = (w & 1) * 64;
    const int lr = l & 15, kq = l >> 4;

    f4v acc[4][4] = {};
    const int NK = K >> 5;

    s8v stg[8];
    #pragma unroll
    for (int i = 0; i < 8; i++) stg[i] = *(const s8v*)gsrc[i];

    for (int kc = 0; kc < NK; kc++) {
        if (kc) __syncthreads();
        #pragma unroll
        for (int i = 0; i < 8; i++) *(s8v*)(lds + ldst[i]) = stg[i];
        __syncthreads();
        if (kc + 1 < NK) {
            const int ko = (kc + 1) * 32;
            #pragma unroll
            for (int i = 0; i < 8; i++) stg[i] = *(const s8v*)(gsrc[i] + ko);
        }
        #define LDR(T, row) (*(const s8v*)(lds + (T) * 4096 + (row) * 32 + ((kq ^ ((row) & 3)) << 3)))
        s8v bh[4], bl[4];
        #pragma unroll
        for (int tn = 0; tn < 4; tn++) {
            int rb = wc + tn * 16 + lr;
            bh[tn] = LDR(2, rb);
            bl[tn] = LDR(3, rb);
        }
        #pragma unroll
        for (int tm = 0; tm < 4; tm++) {
            int ra = wr + tm * 16 + lr;
            s8v ah = LDR(0, ra);
            s8v al = LDR(1, ra);
            #pragma unroll
            for (int tn = 0; tn < 4; tn++) {
                acc[tm][tn] = __builtin_amdgcn_mfma_f32_16x16x32_bf16(ah, bh[tn], acc[tm][tn], 0, 0, 0);
                acc[tm][tn] = __builtin_amdgcn_mfma_f32_16x16x32_bf16(al, bh[tn], acc[tm][tn], 0, 0, 0);
                acc[tm][tn] = __builtin_amdgcn_mfma_f32_16x16x32_bf16(ah, bl[tn], acc[tm][tn], 0, 0, 0);
            }
        }
        #undef LDR
    }

    float s1 = 0.f, s2 = 0.f;
    #pragma unroll
    for (int tm = 0; tm < 4; tm++) {
        #pragma unroll
        for (int rg = 0; rg < 4; rg++) {
            int row = brow + wr + tm * 16 + kq * 4 + rg;
            if (row < M) {
                #pragma unroll
                for (int tn = 0; tn < 4; tn++) {
                    int col = bcol + wc + tn * 16 + lr;
                    float v = acc[tm][tn][rg];
                    if (BIAS) v += bias[col];
                    if (RELU) v = fmaxf(v, 0.f);
                    if (OB16) Ch[(size_t)row * ldc + col] = f2b(v);
                    else      Cf[(size_t)row * ldc + col] = v;
                    if (STATS) { s1 += v; s2 += v * v; }
                }
            }
        }
    }
    if (STATS) {
        __syncthreads();
        red[t] = s1; __syncthreads();
        for (int o = 128; o; o >>= 1) { if (t < o) red[t] += red[t + o]; __syncthreads(); }
        if (t == 0) atomicAdd(&stats[0], red[0]);
        __syncthreads();
        red[t] = s2; __syncthreads();
        for (int o = 128; o; o >>= 1) { if (t < o) red[t] += red[t + o]; __syncthreads(); }
        if (t == 0) atomicAdd(&stats[1], red[0]);
    }
}

// ---------------- fp32 tiled GEMM (tiny-K shapes: geo K=6, pri K=33, cls2) ----------------
template<bool BIAS, bool RELU, bool STATS>
__global__ __launch_bounds__(256) void sgemm_k(
    const float* __restrict__ A, const float* __restrict__ B,
    const float* __restrict__ bias, float* __restrict__ C,
    int M, int K, int N, int ldc, float* __restrict__ stats)
{
    const int BK = 16;
    const int r = blockIdx.z;
    B += (size_t)r * K * N;
    C += (size_t)r * M * ldc;
    __shared__ float As[16][65];
    __shared__ float Bs[16][64];
    int tid = threadIdx.x;
    int tx = tid & 15, ty = tid >> 4;
    int brow = blockIdx.x * 64, bcol = blockIdx.y * 64;
    float acc[4][4] = {};
    for (int k0 = 0; k0 < K; k0 += BK) {
        #pragma unroll
        for (int i = 0; i < 4; i++) {
            int e = tid + 256 * i;
            int ar = e >> 4, ak = e & 15;
            int gr = brow + ar, gk = k0 + ak;
            As[ak][ar] = (gr < M && gk < K) ? A[(size_t)gr * K + gk] : 0.f;
            int bk = e >> 6, bn = e & 63;
            int gbk = k0 + bk, gbn = bcol + bn;
            Bs[bk][bn] = (gbk < K && gbn < N) ? B[(size_t)gbk * N + gbn] : 0.f;
        }
        __syncthreads();
        #pragma unroll
        for (int k = 0; k < BK; k++) {
            float ra[4], rb[4];
            #pragma unroll
            for (int i = 0; i < 4; i++) ra[i] = As[k][ty * 4 + i];
            #pragma unroll
            for (int j = 0; j < 4; j++) rb[j] = Bs[k][tx * 4 + j];
            #pragma unroll
            for (int i = 0; i < 4; i++)
                #pragma unroll
                for (int j = 0; j < 4; j++)
                    acc[i][j] = fmaf(ra[i], rb[j], acc[i][j]);
        }
        __syncthreads();
    }
    float s1 = 0.f, s2 = 0.f;
    #pragma unroll
    for (int i = 0; i < 4; i++) {
        int row = brow + ty * 4 + i;
        #pragma unroll
        for (int j = 0; j < 4; j++) {
            int col = bcol + tx * 4 + j;
            if (row < M && col < N) {
                float v = acc[i][j];
                if (BIAS) v += bias[col];
                if (RELU) v = v > 0.f ? v : 0.f;
                C[(size_t)row * ldc + col] = v;
                if (STATS) { s1 += v; s2 += v * v; }
            }
        }
    }
    if (STATS) {
        __shared__ float red[256];
        __syncthreads();
        red[tid] = s1; __syncthreads();
        for (int o = 128; o; o >>= 1) { if (tid < o) red[tid] += red[tid + o]; __syncthreads(); }
        if (tid == 0) atomicAdd(&stats[0], red[0]);
        __syncthreads();
        red[tid] = s2; __syncthreads();
        for (int o = 128; o; o >>= 1) { if (tid < o) red[tid] += red[tid + o]; __syncthreads(); }
        if (tid == 0) atomicAdd(&stats[1], red[0]);
    }
}

// scalar-LN of a 128-col block of H (pre-offset) from RAW sums (finalized inline),
// fused bf16 hi/lo split into hi/lo (pre-offset).
__global__ __launch_bounds__(256) void enc_norm_k(float* __restrict__ H, const float* __restrict__ w,
                           const float* __restrict__ b, const float* __restrict__ stats,
                           float cntinv, u16* __restrict__ hi, u16* __restrict__ lo)
{
    int i = blockIdx.x * 256 + threadIdx.x;   // float4 index within the 128-col block
    if (i >= Nn * 32) return;
    int n = i >> 5, c4 = i & 31;
    float m = stats[0] * cntinv;
    float var = stats[1] * cntinv - m * m;
    float s = 1.f / (sqrtf(fmaxf(var, 0.f)) + EPS);
    float4 wv = ((const float4*)w)[c4];
    float4 bv = ((const float4*)b)[c4];
    float4* p = (float4*)(H + (size_t)n * FD) + c4;
    float4 v = *p;
    v.x = (v.x - m) * s * wv.x + bv.x;
    v.y = (v.y - m) * s * wv.y + bv.y;
    v.z = (v.z - m) * s * wv.z + bv.z;
    v.w = (v.w - m) * s * wv.w + bv.w;
    *p = v;
    ushort4 hh, ll;
    hh.x = f2b(v.x); ll.x = f2b(v.x - b2f(hh.x));
    hh.y = f2b(v.y); ll.y = f2b(v.y - b2f(hh.y));
    hh.z = f2b(v.z); ll.z = f2b(v.z - b2f(hh.z));
    hh.w = f2b(v.w); ll.w = f2b(v.w - b2f(hh.w));
    ((ushort4*)(hi + (size_t)n * FD))[c4] = hh;
    ((ushort4*)(lo + (size_t)n * FD))[c4] = ll;
}

// qi[r,n,h] = xr[r,n,:] . q[:,h] ; kj likewise. One wave per (r,n) row. XR is bf16.
__global__ __launch_bounds__(256) void proj_qk_k(const u16* __restrict__ xr,
    const float* __restrict__ q, const float* __restrict__ kk,
    float* __restrict__ qi, float* __restrict__ kj)
{
    int row = blockIdx.x * 4 + (threadIdx.x >> 6);
    int lane = threadIdx.x & 63;
    if (row >= 3 * Nn) return;
    const u16* xrow = xr + (size_t)row * FD;
    float pq[8] = {}, pk[8] = {};
    #pragma unroll
    for (int j = 0; j < 6; j++) {
        int c = lane + 64 * j;
        float x = b2f(xrow[c]);
        #pragma unroll
        for (int h = 0; h < 8; h++) {
            pq[h] = fmaf(x, q[c * 8 + h], pq[h]);
            pk[h] = fmaf(x, kk[c * 8 + h], pk[h]);
        }
    }
    #pragma unroll
    for (int o = 32; o; o >>= 1) {
        #pragma unroll
        for (int h = 0; h < 8; h++) {
            pq[h] += __shfl_down(pq[h], o);
            pk[h] += __shfl_down(pk[h], o);
        }
    }
    if (lane == 0) {
        #pragma unroll
        for (int h = 0; h < 8; h++) {
            qi[(size_t)row * 8 + h] = pq[h];
            kj[(size_t)row * 8 + h] = pk[h];
        }
    }
}

__global__ void edge_count_k(const int* __restrict__ e0, const int* __restrict__ e1,
                             const int* __restrict__ e2, int* __restrict__ cnt)
{
    int e = blockIdx.x * 256 + threadIdx.x;
    if (e >= ETOT) return;
    int r = e / EREL, i = e - r * EREL;
    const int* ei = (r == 0) ? e0 : (r == 1) ? e1 : e2;
    atomicAdd(&cnt[ei[EREL + i]], 1);
}

__global__ void edge_fill_k(const int* __restrict__ e0, const int* __restrict__ e1,
                            const int* __restrict__ e2, int* __restrict__ cursor,
                            int* __restrict__ eidx)
{
    int e = blockIdx.x * 256 + threadIdx.x;
    if (e >= ETOT) return;
    int r = e / EREL, i = e - r * EREL;
    const int* ei = (r == 0) ? e0 : (r == 1) ? e1 : e2;
    int src = ei[i], dst = ei[EREL + i];
    int pos = atomicAdd(&cursor[dst], 1);
    eidx[pos] = src | (r << 24);
}

__global__ __launch_bounds__(1024) void scan_k(const int* __restrict__ cnt,
                                               int* __restrict__ rowptr, int* __restrict__ cursor)
{
    __shared__ int lds[1024];
    __shared__ int carry;
    int t = threadIdx.x;
    if (t == 0) carry = 0;
    __syncthreads();
    for (int base = 0; base < Nn; base += 1024) {
        int i = base + t;
        int v = (i < Nn) ? cnt[i] : 0;
        lds[t] = v; __syncthreads();
        for (int o = 1; o < 1024; o <<= 1) {
            int x = (t >= o) ? lds[t - o] : 0;
            __syncthreads();
            lds[t] += x;
            __syncthreads();
        }
        int c = carry;
        if (i < Nn) { int ex = c + lds[t] - v; rowptr[i] = ex; cursor[i] = ex; }
        __syncthreads();
        if (t == 1023) carry = c + lds[1023];
        __syncthreads();
    }
    if (t == 0) rowptr[Nn] = carry;
}

__global__ void gcount_k(const int* __restrict__ batch, int* __restrict__ gcnt)
{
    int n = blockIdx.x * 256 + threadIdx.x;
    if (n >= Nn) return;
    atomicAdd(&gcnt[batch[n]], 1);
}

// RGAT aggregation + fused elu/residual/per-graph-stats. One wave per dst node (CSR).
// Softmax node-local. Requires Nn % 4 == 0 (no partial blocks -> barriers safe).
__global__ __launch_bounds__(256) void aggr_k(const u16* __restrict__ xr,
    const float* __restrict__ qi, const float* __restrict__ kj,
    const int* __restrict__ rowptr, const int* __restrict__ eidx,
    const float* __restrict__ bias, const float* __restrict__ hin,
    const int* __restrict__ batch, float* __restrict__ out,
    float* __restrict__ gsum, float* __restrict__ gsq)
{
    __shared__ float ls[NG], lq[NG];
    int t = threadIdx.x;
    if (t < NG) { ls[t] = 0.f; lq[t] = 0.f; }
    __syncthreads();
    int node = blockIdx.x * 4 + (t >> 6);
    int lane = t & 63;
    int e0 = rowptr[node], e1 = rowptr[node + 1];
    float qv = (lane < 24) ? qi[(size_t)(lane >> 3) * Nn * 8 + (size_t)node * 8 + (lane & 7)] : 0.f;
    float den = 0.f;
    for (int e = e0; e < e1; e++) {
        int p = eidx[e];
        int srcn = p & 0xFFFFFF, et = p >> 24;
        float kv = (lane < 8) ? kj[((size_t)et * Nn + srcn) * 8 + lane] : 0.f;
        float qq = __shfl(qv, et * 8 + (lane & 7));
        float al = qq + kv;
        al = (al > 0.f) ? al : 0.2f * al;
        den += __expf(al);
    }
    int hd[6]; float rcp[6];
    #pragma unroll
    for (int j = 0; j < 6; j++) {
        hd[j] = (lane + 64 * j) / 48;
        float dh = __shfl(den, hd[j]);
        rcp[j] = 1.f / (dh + 1e-16f);
    }
    float acc[6] = {};
    for (int e = e0; e < e1; e++) {
        int p = eidx[e];
        int srcn = p & 0xFFFFFF, et = p >> 24;
        float kv = (lane < 8) ? kj[((size_t)et * Nn + srcn) * 8 + lane] : 0.f;
        float qq = __shfl(qv, et * 8 + (lane & 7));
        float al = qq + kv;
        al = (al > 0.f) ? al : 0.2f * al;
        float ex = __expf(al);
        const u16* row = xr + ((size_t)et * Nn + srcn) * FD;
        #pragma unroll
        for (int j = 0; j < 6; j++) {
            float a = __shfl(ex, hd[j]) * rcp[j];
            acc[j] = fmaf(a, b2f(row[lane + 64 * j]), acc[j]);
        }
    }
    // fused epilogue: elu + residual + write + per-graph stats
    float s1 = 0.f, s2 = 0.f;
    #pragma unroll
    for (int j = 0; j < 6; j++) {
        int c = lane + 64 * j;
        float v = acc[j] + bias[c];
        v = (v > 0.f) ? v : expm1f(v);
        v += hin[(size_t)node * FD + c];
        out[(size_t)node * FD + c] = v;
        s1 += v; s2 += v * v;
    }
    #pragma unroll
    for (int o = 32; o; o >>= 1) { s1 += __shfl_down(s1, o); s2 += __shfl_down(s2, o); }
    int g = batch[node];   // wave-uniform
    if (lane == 0) { atomicAdd(&ls[g], s1); atomicAdd(&lq[g], s2); }
    __syncthreads();
    if (t < NG && (ls[t] != 0.f || lq[t] != 0.f)) {
        atomicAdd(&gsum[t], ls[t]);
        atomicAdd(&gsq[t], lq[t]);
    }
}

// graph-LN (stats finalized inline from raw sums) + fused bf16 hi/lo split
__global__ __launch_bounds__(256) void gnorm_split_k(float* __restrict__ y,
    const int* __restrict__ batch, const float* __restrict__ gsum, const float* __restrict__ gsq,
    const int* __restrict__ gcnt, const float* __restrict__ w, const float* __restrict__ b,
    u16* __restrict__ hi, u16* __restrict__ lo)
{
    int i = blockIdx.x * 256 + threadIdx.x;   // float4 index
    if (i >= Nn * (FD / 4)) return;
    int n = i / 96, c4 = i - n * 96;
    int g = batch[n];
    float norm = fmaxf((float)gcnt[g], 1.f) * (float)FD;
    float m = gsum[g] / norm;
    float var = gsq[g] / norm - m * m;
    float rstd = rsqrtf(var + EPS);
    float4 wv = ((const float4*)w)[c4];
    float4 bv = ((const float4*)b)[c4];
    float4 v = ((const float4*)y)[i];
    v.x = (v.x - m) * rstd * wv.x + bv.x;
    v.y = (v.y - m) * rstd * wv.y + bv.y;
    v.z = (v.z - m) * rstd * wv.z + bv.z;
    v.w = (v.w - m) * rstd * wv.w + bv.w;
    ((float4*)y)[i] = v;
    ushort4 hh, ll;
    hh.x = f2b(v.x); ll.x = f2b(v.x - b2f(hh.x));
    hh.y = f2b(v.y); ll.y = f2b(v.y - b2f(hh.y));
    hh.z = f2b(v.z); ll.z = f2b(v.z - b2f(hh.z));
    hh.w = f2b(v.w); ll.w = f2b(v.w - b2f(hh.w));
    ((ushort4*)hi)[i] = hh;
    ((ushort4*)lo)[i] = ll;
}

__global__ void softmax_prior_k(const float* __restrict__ logits, float* __restrict__ prior)
{
    int n = blockIdx.x * 8 + (threadIdx.x >> 5);
    int l = threadIdx.x & 31;
    if (n >= Nn) return;
    float v = logits[n * 32 + l];
    float m = v;
    #pragma unroll
    for (int o = 16; o; o >>= 1) m = fmaxf(m, __shfl_xor(m, o, 32));
    float e = __expf(v - m);
    float s = e;
    #pragma unroll
    for (int o = 16; o; o >>= 1) s += __shfl_xor(s, o, 32);
    prior[(size_t)n * 33 + l] = e / s;
    if (l == 0) prior[(size_t)n * 33 + 32] = 1.f / s;
}

extern "C" void kernel_launch(void* const* d_in, const int* in_sizes, int n_in,
                              void* d_out, int out_size, void* d_ws, size_t ws_size,
                              hipStream_t stream)
{
    const float* x_visual = (const float*)d_in[0];
    const float* x_geom   = (const float*)d_in[1];
    const float* x_prior  = (const float*)d_in[2];
    const int* ei0   = (const int*)d_in[3];
    const int* ei1   = (const int*)d_in[4];
    const int* ei2   = (const int*)d_in[5];
    const int* batch = (const int*)d_in[6];
    const float* vis_W = (const float*)d_in[7];  const float* vis_b = (const float*)d_in[8];
    const float* vis_lnw = (const float*)d_in[9]; const float* vis_lnb = (const float*)d_in[10];
    const float* geo_W = (const float*)d_in[11]; const float* geo_b = (const float*)d_in[12];
    const float* geo_lnw = (const float*)d_in[13]; const float* geo_lnb = (const float*)d_in[14];
    const float* pri_W = (const float*)d_in[15]; const float* pri_b = (const float*)d_in[16];
    const float* pri_lnw = (const float*)d_in[17]; const float* pri_lnb = (const float*)d_in[18];
    const float* rgat_W[2]    = { (const float*)d_in[19], (const float*)d_in[25] };
    const float* rgat_q[2]    = { (const float*)d_in[20], (const float*)d_in[26] };
    const float* rgat_kk[2]   = { (const float*)d_in[21], (const float*)d_in[27] };
    const float* rgat_bias[2] = { (const float*)d_in[22], (const float*)d_in[28] };
    const float* ln_w[2]      = { (const float*)d_in[23], (const float*)d_in[29] };
    const float* ln_b[2]      = { (const float*)d_in[24], (const float*)d_in[30] };
    const float* cls_W1 = (const float*)d_in[31]; const float* cls_b1 = (const float*)d_in[32];
    const float* cls_W2 = (const float*)d_in[33]; const float* cls_b2 = (const float*)d_in[34];
    float* OUT = (float*)d_out;

    // ---------------- workspace layout ----------------
    float* ws = (float*)d_ws;
    float* XRreg = ws;                         // 3*Nn*FD floats reserved (92.2 MB region)
    u16*   XR16  = (u16*)XRreg;                // XR stored bf16: first 46 MB of the region
    float* HCAT  = XRreg + (size_t)3 * Nn * FD;
    float* HA    = HCAT + (size_t)Nn * FD;
    float* HB    = HA + (size_t)Nn * FD;
    float* PRIOR = HB + (size_t)Nn * FD;       // Nn*33
    float* QI    = PRIOR + (size_t)Nn * 33;
    float* KJ    = QI + (size_t)3 * Nn * 8;
    u16* HS0_HI  = (u16*)(KJ + (size_t)3 * Nn * 8);   // HCAT split
    u16* HS0_LO  = HS0_HI + (size_t)Nn * FD;
    u16* HS1_HI  = HS0_LO + (size_t)Nn * FD;          // HA split
    u16* HS1_LO  = HS1_HI + (size_t)Nn * FD;
    u16* RW_HI   = HS1_LO + (size_t)Nn * FD;   // 2*3*384*384
    u16* RW_LO   = RW_HI + (size_t)2 * 3 * 384 * 384;
    u16* VW_HI   = RW_LO + (size_t)2 * 3 * 384 * 384; // 128*1024
    u16* VW_LO   = VW_HI + (size_t)128 * 1024;
    u16* CW_HI   = VW_LO + (size_t)128 * 1024;        // 128*384
    u16* CW_LO   = CW_HI + (size_t)128 * 384;
    float* STATS = (float*)(CW_LO + (size_t)128 * 384); // 2
    float* GSUM  = STATS + 2;                  // 64
    float* GSQ   = GSUM + 64;
    int* CNT    = (int*)(GSQ + 64);
    int* ROWPTR = CNT + Nn;
    int* CURSOR = ROWPTR + Nn + 1;
    int* EIDX   = CURSOR + Nn;
    int* GCNT   = EIDX + ETOT;
    // aliases into the XR region (temporally dead sub-ranges):
    u16* VA_HI = (u16*)XRreg;                  // x_visual split [0,82MB): dead after vis gemm
    u16* VA_LO = VA_HI + (size_t)Nn * 1024;
    float* CLSH = XRreg;                       // classifier hidden [0,10.3MB): after last aggr
    u16* HS2_HI = (u16*)(XRreg + (size_t)12 * 1000 * 1000); // HB split [48MB,78.7MB): after last aggr
    u16* HS2_LO = HS2_HI + (size_t)Nn * FD;

    // ---------------- CSR build (reused by all 4 RGAT calls) ----------------
    hipMemsetAsync(CNT, 0, Nn * sizeof(int), stream);
    edge_count_k<<<cdiv(ETOT, 256), 256, 0, stream>>>(ei0, ei1, ei2, CNT);
    scan_k<<<1, 1024, 0, stream>>>(CNT, ROWPTR, CURSOR);
    edge_fill_k<<<cdiv(ETOT, 256), 256, 0, stream>>>(ei0, ei1, ei2, CURSOR, EIDX);
    hipMemsetAsync(GCNT, 0, 64 * sizeof(int), stream);
    gcount_k<<<cdiv(Nn, 256), 256, 0, stream>>>(batch, GCNT);

    // ---------------- weight + x_visual conversions ----------------
    tsplit_k<<<cdiv(3 * 384 * 384, 256), 256, 0, stream>>>(rgat_W[0], RW_HI, RW_LO, 384, 384, 3 * 384 * 384);
    tsplit_k<<<cdiv(3 * 384 * 384, 256), 256, 0, stream>>>(rgat_W[1], RW_HI + 3 * 384 * 384, RW_LO + 3 * 384 * 384, 384, 384, 3 * 384 * 384);
    tsplit_k<<<cdiv(1024 * 128, 256), 256, 0, stream>>>(vis_W, VW_HI, VW_LO, 1024, 128, 1024 * 128);
    tsplit_k<<<cdiv(384 * 128, 256), 256, 0, stream>>>(cls_W1, CW_HI, CW_LO, 384, 128, 384 * 128);
    split_k<<<cdiv(Nn * 1024 / 4, 256), 256, 0, stream>>>(x_visual, VA_HI, VA_LO, Nn * 1024 / 4);

    const int MB = cdiv(Nn, 128);   // 157

    // ---------------- vis encoder (MFMA) -> HCAT[:,0:128) ----------------
    hipMemsetAsync(STATS, 0, 2 * sizeof(float), stream);
    mgemm_k<true, true, true, false><<<dim3(MB, 1, 1), 256, 0, stream>>>(
        VA_HI, VA_LO, VW_HI, VW_LO, vis_b, HCAT, Nn, 1024, FD, 0, STATS);
    enc_norm_k<<<cdiv(Nn * 32, 256), 256, 0, stream>>>(HCAT, vis_lnw, vis_lnb, STATS, 1.f / ((float)Nn * 128.f), HS0_HI, HS0_LO);

    // ---------------- geo encoder (fp32, K=6) -> HCAT[:,128:256) ----------------
    dim3 genc(cdiv(Nn, 64), 2, 1);
    hipMemsetAsync(STATS, 0, 2 * sizeof(float), stream);
    sgemm_k<true, true, true><<<genc, 256, 0, stream>>>(x_geom, geo_W, geo_b, HCAT + 128, Nn, 6, 128, FD, STATS);
    enc_norm_k<<<cdiv(Nn * 32, 256), 256, 0, stream>>>(HCAT + 128, geo_lnw, geo_lnb, STATS, 1.f / ((float)Nn * 128.f), HS0_HI + 128, HS0_LO + 128);

    for (int t = 0; t < 2; t++) {
        // prior encoder (fp32, K=33) -> HCAT[:,256:384)
        const float* pin = t ? PRIOR : x_prior;
        hipMemsetAsync(STATS, 0, 2 * sizeof(float), stream);
        sgemm_k<true, true, true><<<genc, 256, 0, stream>>>(pin, pri_W, pri_b, HCAT + 256, Nn, 33, 128, FD, STATS);
        enc_norm_k<<<cdiv(Nn * 32, 256), 256, 0, stream>>>(HCAT + 256, pri_lnw, pri_lnb, STATS, 1.f / ((float)Nn * 128.f), HS0_HI + 256, HS0_LO + 256);

        float* hin = HCAT;
        for (int L = 0; L < 2; L++) {
            float* hout = L ? HB : HA;
            const u16* ahi = L ? HS1_HI : HS0_HI;
            const u16* alo = L ? HS1_LO : HS0_LO;
            u16* shi = L ? HS2_HI : HS1_HI;
            u16* slo = L ? HS2_LO : HS1_LO;
            mgemm_k<false, false, false, true><<<dim3(MB, 3, 3), 256, 0, stream>>>(
                ahi, alo, RW_HI + (size_t)L * 3 * 384 * 384, RW_LO + (size_t)L * 3 * 384 * 384,
                nullptr, XR16, Nn, 384, FD, 384 * 384, nullptr);
            proj_qk_k<<<cdiv(3 * Nn, 4), 256, 0, stream>>>(XR16, rgat_q[L], rgat_kk[L], QI, KJ);
            hipMemsetAsync(GSUM, 0, 128 * sizeof(float), stream);  // GSUM+GSQ contiguous
            aggr_k<<<cdiv(Nn, 4), 256, 0, stream>>>(XR16, QI, KJ, ROWPTR, EIDX, rgat_bias[L],
                                                    hin, batch, hout, GSUM, GSQ);
            gnorm_split_k<<<cdiv(Nn * 96, 256), 256, 0, stream>>>(hout, batch, GSUM, GSQ, GCNT, ln_w[L], ln_b[L], shi, slo);
            hin = hout;
        }

        // classifier: cls1 (MFMA, reads HS2 split) -> CLSH, cls2 (fp32) -> OUT
        mgemm_k<true, true, false, false><<<dim3(MB, 1, 1), 256, 0, stream>>>(
            HS2_HI, HS2_LO, CW_HI, CW_LO, cls_b1, CLSH, Nn, 384, 128, 0, nullptr);
        sgemm_k<true, false, false><<<dim3(cdiv(Nn, 64), 1, 1), 256, 0, stream>>>(
            CLSH, cls_W2, cls_b2, OUT, Nn, 128, 32, 32, nullptr);

        if (t == 0)
            softmax_prior_k<<<cdiv(Nn, 8), 256, 0, stream>>>(OUT, PRIOR);
    }
}